// Round 1
// baseline (92.923 us; speedup 1.0000x reference)
//
#include <hip/hip_runtime.h>
#include <hip/hip_bf16.h>
#include <math.h>

// Problem constants (from reference)
#define NB    128
#define NT_ALL 197
#define NT    196
#define ND    768
#define NORG  5
#define NE    8
#define NCLS  100
#define NTOK  (NB * NT)       // 25088
#define RW_ROWS (ND + NORG)   // 773

// Output layout (flat, concatenated in return order):
//   logits  : NB*NCLS            = 12800   @ 0
//   aux_org : NB*NORG            = 640     @ 12800
//   probs   : NB*NT*NE           = 200704  @ 13440
//   entropy : NB*NT              = 25088   @ 214144

// ---------------------------------------------------------------------------
// Router kernel: one wave (64 lanes) per token.
// router_w staged in LDS transposed [e][d] with padded stride (776) so each
// lane's float4 read is a conflict-free ds_read_b128.
// ---------------------------------------------------------------------------
__global__ __launch_bounds__(256) void router_kernel(
    const float* __restrict__ tokens,    // (NB, NT_ALL, ND)
    const float* __restrict__ priors,    // (NB, NORG)
    const float* __restrict__ rw,        // (RW_ROWS, NE) row-major
    const float* __restrict__ rb,        // (NE,)
    float* __restrict__ probs_out,       // (NTOK, NE)
    float* __restrict__ ent_out)         // (NTOK,)
{
    __shared__ __align__(16) float s_rwt[NE][776];  // transposed + padded

    // Stage router_w (773x8 = 6184 floats) transposed into LDS.
    for (int i = threadIdx.x; i < RW_ROWS * NE; i += 256) {
        int d = i >> 3;
        int e = i & 7;
        s_rwt[e][d] = rw[i];
    }
    __syncthreads();

    const int wid  = threadIdx.x >> 6;
    const int lane = threadIdx.x & 63;
    const int token = blockIdx.x * 4 + wid;   // grid = 6272 blocks * 4 waves = 25088
    if (token >= NTOK) return;

    const int b = token / NT;
    const int t = token - b * NT;
    const float* xp = tokens + ((size_t)b * NT_ALL + 1 + t) * ND;

    float acc[NE];
#pragma unroll
    for (int e = 0; e < NE; ++e) acc[e] = 0.f;

    // 768 dims: 3 rounds, each lane reads one float4 (coalesced 16B/lane).
#pragma unroll
    for (int r = 0; r < 3; ++r) {
        const int d = r * 256 + lane * 4;
        const float4 v = *reinterpret_cast<const float4*>(xp + d);
#pragma unroll
        for (int e = 0; e < NE; ++e) {
            const float4 w = *reinterpret_cast<const float4*>(&s_rwt[e][d]);
            acc[e] = fmaf(v.x, w.x, acc[e]);
            acc[e] = fmaf(v.y, w.y, acc[e]);
            acc[e] = fmaf(v.z, w.z, acc[e]);
            acc[e] = fmaf(v.w, w.w, acc[e]);
        }
    }

    // Butterfly reduce across the 64-lane wave (all lanes end with full sums).
#pragma unroll
    for (int off = 32; off; off >>= 1) {
#pragma unroll
        for (int e = 0; e < NE; ++e)
            acc[e] += __shfl_xor(acc[e], off, 64);
    }

    // Organ-prior part + bias (tiny, redundantly computed by all lanes).
    float pr[NORG];
#pragma unroll
    for (int o = 0; o < NORG; ++o) pr[o] = priors[b * NORG + o];
#pragma unroll
    for (int e = 0; e < NE; ++e) {
        float a = acc[e] + rb[e];
#pragma unroll
        for (int o = 0; o < NORG; ++o)
            a = fmaf(pr[o], s_rwt[e][ND + o], a);
        acc[e] = a;
    }

    // Softmax (8-wide, in-register) + entropy.
    float m = acc[0];
#pragma unroll
    for (int e = 1; e < NE; ++e) m = fmaxf(m, acc[e]);
    float s = 0.f;
#pragma unroll
    for (int e = 0; e < NE; ++e) { acc[e] = expf(acc[e] - m); s += acc[e]; }
    const float inv = 1.f / s;
    float ent = 0.f;
#pragma unroll
    for (int e = 0; e < NE; ++e) {
        acc[e] *= inv;
        ent -= acc[e] * logf(acc[e] + 1e-12f);
    }

    if (lane < NE) probs_out[(size_t)token * NE + lane] = acc[lane];
    if (lane == 0) ent_out[token] = ent;
}

// ---------------------------------------------------------------------------
// CLS head: one block per batch row. Two-pass LayerNorm, then 105 GEMV
// columns (100 cls + 5 aux), one per thread, coalesced weight reads.
// ---------------------------------------------------------------------------
__global__ __launch_bounds__(128) void cls_kernel(
    const float* __restrict__ tokens,    // (NB, NT_ALL, ND)
    const float* __restrict__ ln_g, const float* __restrict__ ln_b,
    const float* __restrict__ cls_w,     // (ND, NCLS)
    const float* __restrict__ cls_b,     // (NCLS,)
    const float* __restrict__ aux_w,     // (ND, NORG)
    const float* __restrict__ aux_b,     // (NORG,)
    float* __restrict__ out_logits,      // (NB, NCLS)
    float* __restrict__ out_aux)         // (NB, NORG)
{
    const int b = blockIdx.x;
    __shared__ __align__(16) float s_x[ND];
    __shared__ float s_r[2];

    const float* xp = tokens + (size_t)b * NT_ALL * ND;  // cls token = t 0

    // Pass 1: load + mean
    float sum = 0.f;
    for (int i = threadIdx.x; i < ND; i += 128) {
        float v = xp[i];
        s_x[i] = v;
        sum += v;
    }
#pragma unroll
    for (int off = 32; off; off >>= 1) sum += __shfl_xor(sum, off, 64);
    if ((threadIdx.x & 63) == 0) s_r[threadIdx.x >> 6] = sum;
    __syncthreads();
    const float mu = (s_r[0] + s_r[1]) * (1.f / ND);
    __syncthreads();

    // Pass 2: variance
    float sq = 0.f;
    for (int i = threadIdx.x; i < ND; i += 128) {
        float dlt = s_x[i] - mu;
        sq += dlt * dlt;
    }
#pragma unroll
    for (int off = 32; off; off >>= 1) sq += __shfl_xor(sq, off, 64);
    if ((threadIdx.x & 63) == 0) s_r[threadIdx.x >> 6] = sq;
    __syncthreads();
    const float var = (s_r[0] + s_r[1]) * (1.f / ND);
    const float rstd = rsqrtf(var + 1e-5f);
    __syncthreads();

    // Normalize in LDS
    for (int i = threadIdx.x; i < ND; i += 128)
        s_x[i] = (s_x[i] - mu) * rstd * ln_g[i] + ln_b[i];
    __syncthreads();

    // GEMV: column c per thread (coalesced across threads per d).
    for (int c = threadIdx.x; c < NCLS + NORG; c += 128) {
        if (c < NCLS) {
            float a = cls_b[c];
#pragma unroll 8
            for (int d = 0; d < ND; ++d)
                a = fmaf(s_x[d], cls_w[d * NCLS + c], a);
            out_logits[b * NCLS + c] = a;
        } else {
            const int o = c - NCLS;
            float a = aux_b[o];
#pragma unroll 8
            for (int d = 0; d < ND; ++d)
                a = fmaf(s_x[d], aux_w[d * NORG + o], a);
            out_aux[b * NORG + o] = a;
        }
    }
}

extern "C" void kernel_launch(void* const* d_in, const int* in_sizes, int n_in,
                              void* d_out, int out_size, void* d_ws, size_t ws_size,
                              hipStream_t stream) {
    const float* tokens = (const float*)d_in[0];
    const float* priors = (const float*)d_in[1];
    const float* rw     = (const float*)d_in[2];
    const float* rb     = (const float*)d_in[3];
    // d_in[4..7] = w1,b1,w2,b2 : dead code (MoE output unused by reference)
    const float* ln_g   = (const float*)d_in[8];
    const float* ln_b   = (const float*)d_in[9];
    const float* cls_w  = (const float*)d_in[10];
    const float* cls_b  = (const float*)d_in[11];
    const float* aux_w  = (const float*)d_in[12];
    const float* aux_b  = (const float*)d_in[13];

    float* out = (float*)d_out;
    float* out_logits = out;                       // 12800
    float* out_aux    = out + NB * NCLS;           // +640
    float* out_probs  = out + NB * NCLS + NB * NORG;          // +200704
    float* out_ent    = out + NB * NCLS + NB * NORG + NTOK * NE;

    cls_kernel<<<NB, 128, 0, stream>>>(tokens, ln_g, ln_b, cls_w, cls_b,
                                       aux_w, aux_b, out_logits, out_aux);

    router_kernel<<<NTOK / 4, 256, 0, stream>>>(tokens, priors, rw, rb,
                                                out_probs, out_ent);
}

// Round 2
// 67.130 us; speedup vs baseline: 1.3842x; 1.3842x over previous
//
#include <hip/hip_runtime.h>
#include <hip/hip_bf16.h>
#include <math.h>

// Problem constants (from reference)
#define NB     128
#define NT_ALL 197
#define NT     196
#define ND     768
#define NORG   5
#define NE     8
#define NCLS   100
#define NCOL   105            // 100 cls + 5 aux columns
#define NTOK   (NB * NT)      // 25088
#define RW_ROWS (ND + NORG)   // 773
#define TOK_PER_BLK 16

// Output layout (flat, concatenated in return order):
//   logits  : NB*NCLS = 12800   @ 0
//   aux_org : NB*NORG = 640     @ 12800
//   probs   : NTOK*NE = 200704  @ 13440
//   entropy : NTOK    = 25088   @ 214144

// ---------------------------------------------------------------------------
// Router: one wave per token, 16 tokens per block (amortize router_w staging).
// router_w staged transposed+padded in LDS -> conflict-free ds_read_b128.
// ---------------------------------------------------------------------------
__global__ __launch_bounds__(256) void router_kernel(
    const float* __restrict__ tokens,    // (NB, NT_ALL, ND)
    const float* __restrict__ priors,    // (NB, NORG)
    const float* __restrict__ rw,        // (RW_ROWS, NE) row-major
    const float* __restrict__ rb,        // (NE,)
    float* __restrict__ probs_out,       // (NTOK, NE)
    float* __restrict__ ent_out)         // (NTOK,)
{
    __shared__ __align__(16) float s_rwt[NE][776];  // transposed + padded

    for (int i = threadIdx.x; i < RW_ROWS * NE; i += 256) {
        s_rwt[i & 7][i >> 3] = rw[i];
    }
    __syncthreads();

    const int wid  = threadIdx.x >> 6;
    const int lane = threadIdx.x & 63;
    const int base = blockIdx.x * TOK_PER_BLK;

    for (int k = 0; k < TOK_PER_BLK / 4; ++k) {
        const int token = base + k * 4 + wid;

        const int b = token / NT;
        const int t = token - b * NT;
        const float* xp = tokens + ((size_t)b * NT_ALL + 1 + t) * ND;

        float acc[NE];
#pragma unroll
        for (int e = 0; e < NE; ++e) acc[e] = 0.f;

#pragma unroll
        for (int r = 0; r < 3; ++r) {
            const int d = r * 256 + lane * 4;
            const float4 v = *reinterpret_cast<const float4*>(xp + d);
#pragma unroll
            for (int e = 0; e < NE; ++e) {
                const float4 w = *reinterpret_cast<const float4*>(&s_rwt[e][d]);
                acc[e] = fmaf(v.x, w.x, acc[e]);
                acc[e] = fmaf(v.y, w.y, acc[e]);
                acc[e] = fmaf(v.z, w.z, acc[e]);
                acc[e] = fmaf(v.w, w.w, acc[e]);
            }
        }

#pragma unroll
        for (int off = 32; off; off >>= 1) {
#pragma unroll
            for (int e = 0; e < NE; ++e)
                acc[e] += __shfl_xor(acc[e], off, 64);
        }

        float pr[NORG];
#pragma unroll
        for (int o = 0; o < NORG; ++o) pr[o] = priors[b * NORG + o];
#pragma unroll
        for (int e = 0; e < NE; ++e) {
            float a = acc[e] + rb[e];
#pragma unroll
            for (int o = 0; o < NORG; ++o)
                a = fmaf(pr[o], s_rwt[e][ND + o], a);
            acc[e] = a;
        }

        float m = acc[0];
#pragma unroll
        for (int e = 1; e < NE; ++e) m = fmaxf(m, acc[e]);
        float s = 0.f;
#pragma unroll
        for (int e = 0; e < NE; ++e) { acc[e] = expf(acc[e] - m); s += acc[e]; }
        const float inv = 1.f / s;
        float ent = 0.f;
#pragma unroll
        for (int e = 0; e < NE; ++e) {
            acc[e] *= inv;
            ent -= acc[e] * logf(acc[e] + 1e-12f);
        }

        if (lane < NE) probs_out[(size_t)token * NE + lane] = acc[lane];
        if (lane == 0) ent_out[token] = ent;
    }
}

// ---------------------------------------------------------------------------
// CLS head v2: 2 blocks per batch row, 512 threads each.
// LN with 8-wave reduce, then GEMV with thread=(column=lane, K-split=wave):
// 96-elem partial dot, 4 independent accumulators, float4 LDS x-reads,
// LDS tree-reduce of the 8 partials.
// ---------------------------------------------------------------------------
__global__ __launch_bounds__(512) void cls_kernel(
    const float* __restrict__ tokens,    // (NB, NT_ALL, ND)
    const float* __restrict__ ln_g, const float* __restrict__ ln_b,
    const float* __restrict__ cls_w,     // (ND, NCLS)
    const float* __restrict__ cls_b,     // (NCLS,)
    const float* __restrict__ aux_w,     // (ND, NORG)
    const float* __restrict__ aux_b,     // (NORG,)
    float* __restrict__ out_logits,      // (NB, NCLS)
    float* __restrict__ out_aux)         // (NB, NORG)
{
    const int b    = blockIdx.x >> 1;
    const int half = blockIdx.x & 1;
    const int t    = threadIdx.x;
    const int lane = t & 63;
    const int wv   = t >> 6;            // 0..7

    __shared__ __align__(16) float s_x[ND];
    __shared__ float s_red[8];
    __shared__ float s_part[8][65];     // padded: column-read conflict-free

    const float* xp = tokens + (size_t)b * NT_ALL * ND;  // cls token

    // mean
    float sum = 0.f;
    for (int i = t; i < ND; i += 512) { float v = xp[i]; s_x[i] = v; sum += v; }
#pragma unroll
    for (int off = 32; off; off >>= 1) sum += __shfl_xor(sum, off, 64);
    if (lane == 0) s_red[wv] = sum;
    __syncthreads();
    float mu = 0.f;
#pragma unroll
    for (int i = 0; i < 8; ++i) mu += s_red[i];
    mu *= (1.f / ND);
    __syncthreads();                    // s_red reuse

    // variance
    float sq = 0.f;
    for (int i = t; i < ND; i += 512) { float d = s_x[i] - mu; sq += d * d; }
#pragma unroll
    for (int off = 32; off; off >>= 1) sq += __shfl_xor(sq, off, 64);
    if (lane == 0) s_red[wv] = sq;
    __syncthreads();
    float var = 0.f;
#pragma unroll
    for (int i = 0; i < 8; ++i) var += s_red[i];
    var *= (1.f / ND);
    const float rstd = rsqrtf(var + 1e-5f);
    __syncthreads();

    // normalize in place (each thread owns its elements)
    for (int i = t; i < ND; i += 512)
        s_x[i] = (s_x[i] - mu) * rstd * ln_g[i] + ln_b[i];
    __syncthreads();

    // GEMV: c = half*64+lane, K-split ks = wv (96 dims each)
    const int c = half * 64 + lane;
    const float* wp; int st;
    if (c < NCLS)      { wp = cls_w + c;            st = NCLS; }
    else if (c < NCOL) { wp = aux_w + (c - NCLS);   st = NORG; }
    else               { wp = aux_w;                st = NORG; }  // idle lanes: harmless reads

    const int d0 = wv * 96;
    const float* w = wp + (size_t)d0 * st;
    const int st2 = 2 * st, st3 = 3 * st, st4 = 4 * st;
    float a0 = 0.f, a1 = 0.f, a2 = 0.f, a3 = 0.f;
#pragma unroll 8
    for (int j = 0; j < 96; j += 4) {
        const float4 x4 = *reinterpret_cast<const float4*>(&s_x[d0 + j]);
        a0 = fmaf(x4.x, w[0],   a0);
        a1 = fmaf(x4.y, w[st],  a1);
        a2 = fmaf(x4.z, w[st2], a2);
        a3 = fmaf(x4.w, w[st3], a3);
        w += st4;
    }
    s_part[wv][lane] = (a0 + a1) + (a2 + a3);
    __syncthreads();

    if (t < 64) {
        float r = 0.f;
#pragma unroll
        for (int i = 0; i < 8; ++i) r += s_part[i][t];
        const int cc = half * 64 + t;
        if (cc < NCLS)
            out_logits[b * NCLS + cc] = r + cls_b[cc];
        else if (cc < NCOL)
            out_aux[b * NORG + (cc - NCLS)] = r + aux_b[cc - NCLS];
    }
}

extern "C" void kernel_launch(void* const* d_in, const int* in_sizes, int n_in,
                              void* d_out, int out_size, void* d_ws, size_t ws_size,
                              hipStream_t stream) {
    const float* tokens = (const float*)d_in[0];
    const float* priors = (const float*)d_in[1];
    const float* rw     = (const float*)d_in[2];
    const float* rb     = (const float*)d_in[3];
    // d_in[4..7] = w1,b1,w2,b2 : dead code (MoE output unused by reference)
    const float* ln_g   = (const float*)d_in[8];
    const float* ln_b   = (const float*)d_in[9];
    const float* cls_w  = (const float*)d_in[10];
    const float* cls_b  = (const float*)d_in[11];
    const float* aux_w  = (const float*)d_in[12];
    const float* aux_b  = (const float*)d_in[13];

    float* out = (float*)d_out;
    float* out_logits = out;                                   // 12800
    float* out_aux    = out + NB * NCLS;                       // +640
    float* out_probs  = out + NB * NCLS + NB * NORG;           // +200704
    float* out_ent    = out + NB * NCLS + NB * NORG + (size_t)NTOK * NE;

    cls_kernel<<<NB * 2, 512, 0, stream>>>(tokens, ln_g, ln_b, cls_w, cls_b,
                                           aux_w, aux_b, out_logits, out_aux);

    router_kernel<<<NTOK / TOK_PER_BLK, 256, 0, stream>>>(tokens, priors, rw, rb,
                                                          out_probs, out_ent);
}

// Round 3
// 45.202 us; speedup vs baseline: 2.0557x; 1.4851x over previous
//
#include <hip/hip_runtime.h>
#include <hip/hip_bf16.h>
#include <math.h>

// Problem constants (from reference)
#define NB     128
#define NT_ALL 197
#define NT     196
#define ND     768
#define NORG   5
#define NE     8
#define NCLS   100
#define NCOL   105            // 100 cls + 5 aux columns
#define NTOK   (NB * NT)      // 25088
#define RW_ROWS (ND + NORG)   // 773
#define TOK_PER_BLK 16        // 4 waves * 2 tokens * 2 k-iters

// Output layout (flat, concatenated in return order):
//   logits  : NB*NCLS = 12800   @ 0
//   aux_org : NB*NORG = 640     @ 12800
//   probs   : NTOK*NE = 200704  @ 13440
//   entropy : NTOK    = 25088   @ 214144

// ---------------------------------------------------------------------------
// Router: one wave processes 2 tokens at a time (ILP), 16 tokens/block.
// router_w staged transposed+padded in LDS; fast softmax tail:
//   ent = ln(s) - (sum p*l)/s  (1 log instead of 8), __expf native exp.
// Prior+bias logits precomputed per batch in cls_kernel (d_ws) when available.
// ---------------------------------------------------------------------------
__global__ __launch_bounds__(256, 4) void router_kernel(
    const float* __restrict__ tokens,    // (NB, NT_ALL, ND)
    const float* __restrict__ priors,    // (NB, NORG)   (fallback path)
    const float* __restrict__ rw,        // (RW_ROWS, NE) row-major
    const float* __restrict__ rb,        // (NE,)        (fallback path)
    const float* __restrict__ pl,        // (NB, NE) prior logits or nullptr
    float* __restrict__ probs_out,       // (NTOK, NE)
    float* __restrict__ ent_out)         // (NTOK,)
{
    __shared__ __align__(16) float s_rwt[NE][776];  // transposed + padded

    for (int i = threadIdx.x; i < RW_ROWS * NE; i += 256)
        s_rwt[i & 7][i >> 3] = rw[i];
    __syncthreads();

    const int wid  = threadIdx.x >> 6;
    const int lane = threadIdx.x & 63;
    const int base = blockIdx.x * TOK_PER_BLK;

#pragma unroll
    for (int k = 0; k < 2; ++k) {
        const int tA = base + wid * 4 + k * 2;
        const int tB = tA + 1;

        const int bA = tA / NT;
        const int bB = tB / NT;
        const float* xpA = tokens + ((size_t)bA * NT_ALL + 1 + (tA - bA * NT)) * ND;
        const float* xpB = tokens + ((size_t)bB * NT_ALL + 1 + (tB - bB * NT)) * ND;

        // All 6 global float4 loads issued up front (independent).
        float4 vA[3], vB[3];
#pragma unroll
        for (int r = 0; r < 3; ++r) {
            const int d = r * 256 + lane * 4;
            vA[r] = *reinterpret_cast<const float4*>(xpA + d);
            vB[r] = *reinterpret_cast<const float4*>(xpB + d);
        }

        float aA[NE], aB[NE];
#pragma unroll
        for (int e = 0; e < NE; ++e) { aA[e] = 0.f; aB[e] = 0.f; }

#pragma unroll
        for (int r = 0; r < 3; ++r) {
            const int d = r * 256 + lane * 4;
#pragma unroll
            for (int e = 0; e < NE; ++e) {
                const float4 w = *reinterpret_cast<const float4*>(&s_rwt[e][d]);
                aA[e] = fmaf(vA[r].x, w.x, aA[e]);
                aA[e] = fmaf(vA[r].y, w.y, aA[e]);
                aA[e] = fmaf(vA[r].z, w.z, aA[e]);
                aA[e] = fmaf(vA[r].w, w.w, aA[e]);
                aB[e] = fmaf(vB[r].x, w.x, aB[e]);
                aB[e] = fmaf(vB[r].y, w.y, aB[e]);
                aB[e] = fmaf(vB[r].z, w.z, aB[e]);
                aB[e] = fmaf(vB[r].w, w.w, aB[e]);
            }
        }

        // Butterfly reduce (two independent chains overlap).
#pragma unroll
        for (int off = 32; off; off >>= 1) {
#pragma unroll
            for (int e = 0; e < NE; ++e) {
                aA[e] += __shfl_xor(aA[e], off, 64);
                aB[e] += __shfl_xor(aB[e], off, 64);
            }
        }

        // Prior + bias logits.
        if (pl) {
#pragma unroll
            for (int e = 0; e < NE; ++e) {
                aA[e] += pl[bA * NE + e];
                aB[e] += pl[bB * NE + e];
            }
        } else {
#pragma unroll
            for (int e = 0; e < NE; ++e) {
                float a0 = aA[e] + rb[e], a1 = aB[e] + rb[e];
#pragma unroll
                for (int o = 0; o < NORG; ++o) {
                    a0 = fmaf(priors[bA * NORG + o], s_rwt[e][ND + o], a0);
                    a1 = fmaf(priors[bB * NORG + o], s_rwt[e][ND + o], a1);
                }
                aA[e] = a0; aB[e] = a1;
            }
        }

        // Fast softmax + entropy:  ent = ln(s) - (sum p*l)/s,  l = logit - max
        float mA = aA[0], mB = aB[0];
#pragma unroll
        for (int e = 1; e < NE; ++e) { mA = fmaxf(mA, aA[e]); mB = fmaxf(mB, aB[e]); }
        float sA = 0.f, sB = 0.f, dA = 0.f, dB = 0.f;
#pragma unroll
        for (int e = 0; e < NE; ++e) {
            const float lA = aA[e] - mA, lB = aB[e] - mB;
            const float pA = __expf(lA), pB = __expf(lB);
            aA[e] = pA; aB[e] = pB;
            sA += pA; sB += pB;
            dA = fmaf(pA, lA, dA);
            dB = fmaf(pB, lB, dB);
        }
        const float invA = 1.f / sA, invB = 1.f / sB;
        const float entA = __logf(sA) - dA * invA;
        const float entB = __logf(sB) - dB * invB;

        // Select this lane's prob via cndmask chain (no dynamic reg index).
        float pvA = aA[0] * invA, pvB = aB[0] * invB;
#pragma unroll
        for (int e = 1; e < NE; ++e) {
            pvA = (lane == e) ? aA[e] * invA : pvA;
            pvB = (lane == e) ? aB[e] * invB : pvB;
        }
        if (lane < NE) {
            probs_out[(size_t)tA * NE + lane] = pvA;
            probs_out[(size_t)tB * NE + lane] = pvB;
        }
        if (lane == 0) { ent_out[tA] = entA; ent_out[tB] = entB; }
    }
}

// ---------------------------------------------------------------------------
// CLS head: 2 blocks per batch row, 512 threads. LN + GEMV (col=lane,
// K-split=wave). half==0 blocks additionally precompute prior logits -> pl.
// ---------------------------------------------------------------------------
__global__ __launch_bounds__(512) void cls_kernel(
    const float* __restrict__ tokens,    // (NB, NT_ALL, ND)
    const float* __restrict__ ln_g, const float* __restrict__ ln_b,
    const float* __restrict__ cls_w,     // (ND, NCLS)
    const float* __restrict__ cls_b,     // (NCLS,)
    const float* __restrict__ aux_w,     // (ND, NORG)
    const float* __restrict__ aux_b,     // (NORG,)
    const float* __restrict__ priors,    // (NB, NORG)
    const float* __restrict__ rw,        // (RW_ROWS, NE)
    const float* __restrict__ rb,        // (NE,)
    float* __restrict__ pl,              // (NB, NE) prior logits or nullptr
    float* __restrict__ out_logits,      // (NB, NCLS)
    float* __restrict__ out_aux)         // (NB, NORG)
{
    const int b    = blockIdx.x >> 1;
    const int half = blockIdx.x & 1;
    const int t    = threadIdx.x;
    const int lane = t & 63;
    const int wv   = t >> 6;            // 0..7

    __shared__ __align__(16) float s_x[ND];
    __shared__ float s_red[8];
    __shared__ float s_part[8][65];

    // Prior logits (independent of everything else in this kernel).
    if (pl && half == 0 && t < NE) {
        float a = rb[t];
#pragma unroll
        for (int o = 0; o < NORG; ++o)
            a = fmaf(priors[b * NORG + o], rw[(ND + o) * NE + t], a);
        pl[b * NE + t] = a;
    }

    const float* xp = tokens + (size_t)b * NT_ALL * ND;  // cls token

    float sum = 0.f;
    for (int i = t; i < ND; i += 512) { float v = xp[i]; s_x[i] = v; sum += v; }
#pragma unroll
    for (int off = 32; off; off >>= 1) sum += __shfl_xor(sum, off, 64);
    if (lane == 0) s_red[wv] = sum;
    __syncthreads();
    float mu = 0.f;
#pragma unroll
    for (int i = 0; i < 8; ++i) mu += s_red[i];
    mu *= (1.f / ND);
    __syncthreads();

    float sq = 0.f;
    for (int i = t; i < ND; i += 512) { float d = s_x[i] - mu; sq += d * d; }
#pragma unroll
    for (int off = 32; off; off >>= 1) sq += __shfl_xor(sq, off, 64);
    if (lane == 0) s_red[wv] = sq;
    __syncthreads();
    float var = 0.f;
#pragma unroll
    for (int i = 0; i < 8; ++i) var += s_red[i];
    var *= (1.f / ND);
    const float rstd = rsqrtf(var + 1e-5f);
    __syncthreads();

    for (int i = t; i < ND; i += 512)
        s_x[i] = (s_x[i] - mu) * rstd * ln_g[i] + ln_b[i];
    __syncthreads();

    const int c = half * 64 + lane;
    const float* wp; int st;
    if (c < NCLS)      { wp = cls_w + c;          st = NCLS; }
    else if (c < NCOL) { wp = aux_w + (c - NCLS); st = NORG; }
    else               { wp = aux_w;              st = NORG; }

    const int d0 = wv * 96;
    const float* w = wp + (size_t)d0 * st;
    const int st2 = 2 * st, st3 = 3 * st, st4 = 4 * st;
    float a0 = 0.f, a1 = 0.f, a2 = 0.f, a3 = 0.f;
#pragma unroll 8
    for (int j = 0; j < 96; j += 4) {
        const float4 x4 = *reinterpret_cast<const float4*>(&s_x[d0 + j]);
        a0 = fmaf(x4.x, w[0],   a0);
        a1 = fmaf(x4.y, w[st],  a1);
        a2 = fmaf(x4.z, w[st2], a2);
        a3 = fmaf(x4.w, w[st3], a3);
        w += st4;
    }
    s_part[wv][lane] = (a0 + a1) + (a2 + a3);
    __syncthreads();

    if (t < 64) {
        float r = 0.f;
#pragma unroll
        for (int i = 0; i < 8; ++i) r += s_part[i][t];
        const int cc = half * 64 + t;
        if (cc < NCLS)
            out_logits[b * NCLS + cc] = r + cls_b[cc];
        else if (cc < NCOL)
            out_aux[b * NORG + (cc - NCLS)] = r + aux_b[cc - NCLS];
    }
}

extern "C" void kernel_launch(void* const* d_in, const int* in_sizes, int n_in,
                              void* d_out, int out_size, void* d_ws, size_t ws_size,
                              hipStream_t stream) {
    const float* tokens = (const float*)d_in[0];
    const float* priors = (const float*)d_in[1];
    const float* rw     = (const float*)d_in[2];
    const float* rb     = (const float*)d_in[3];
    // d_in[4..7] = w1,b1,w2,b2 : dead code (MoE output unused by reference)
    const float* ln_g   = (const float*)d_in[8];
    const float* ln_b   = (const float*)d_in[9];
    const float* cls_w  = (const float*)d_in[10];
    const float* cls_b  = (const float*)d_in[11];
    const float* aux_w  = (const float*)d_in[12];
    const float* aux_b  = (const float*)d_in[13];

    float* out = (float*)d_out;
    float* out_logits = out;                                   // 12800
    float* out_aux    = out + NB * NCLS;                       // +640
    float* out_probs  = out + NB * NCLS + NB * NORG;           // +200704
    float* out_ent    = out + NB * NCLS + NB * NORG + (size_t)NTOK * NE;

    float* pl = (ws_size >= (size_t)(NB * NE) * sizeof(float)) ? (float*)d_ws
                                                               : nullptr;

    cls_kernel<<<NB * 2, 512, 0, stream>>>(tokens, ln_g, ln_b, cls_w, cls_b,
                                           aux_w, aux_b, priors, rw, rb, pl,
                                           out_logits, out_aux);

    router_kernel<<<NTOK / TOK_PER_BLK, 256, 0, stream>>>(
        tokens, priors, rw, rb, pl, out_probs, out_ent);
}

// Round 4
// 41.971 us; speedup vs baseline: 2.2140x; 1.0770x over previous
//
#include <hip/hip_runtime.h>
#include <hip/hip_bf16.h>
#include <math.h>

// Problem constants (from reference)
#define NB     128
#define NT_ALL 197
#define NT     196
#define ND     768
#define NORG   5
#define NE     8
#define NCLS   100
#define NCOL   105            // 100 cls + 5 aux columns
#define NTOK   (NB * NT)      // 25088
#define RW_ROWS (ND + NORG)   // 773

#define RBLKS  (NTOK / 32)    // 784 router blocks (32 tokens each)
#define CBLKS  (NB * 2)       // 256 cls blocks
#define KSL    96             // dims per k-slice (8 slices * 96 = 768)

// Output layout (flat, concatenated in return order):
//   logits  : NB*NCLS = 12800   @ 0
//   aux_org : NB*NORG = 640     @ 12800
//   probs   : NTOK*NE = 200704  @ 13440
//   entropy : NTOK    = 25088   @ 214144

// ---------------------------------------------------------------------------
// Fused kernel. Blocks [0,784): router. Blocks [784,1040): CLS head.
//
// Router mapping: 256 threads = 4 waves; each 8-lane group owns ONE token
// (lane = 8*token_group + k_slice). Each lane: 96-dim x 8-expert partial dot
// (global float4 token reads, LDS broadcast weight reads), then a 3-stage
// __shfl_xor{1,2,4} reduce, then a fully per-lane softmax/entropy tail.
// Weights in LDS as [e][slice][100] so the 8 slice addresses of one
// ds_read_b128 hit disjoint bank quads (conflict-free broadcast).
// ---------------------------------------------------------------------------
__global__ __launch_bounds__(256, 4) void fused_kernel(
    const float* __restrict__ tokens,    // (NB, NT_ALL, ND)
    const float* __restrict__ priors,    // (NB, NORG)
    const float* __restrict__ rw,        // (RW_ROWS, NE) row-major
    const float* __restrict__ rb,        // (NE,)
    const float* __restrict__ ln_g, const float* __restrict__ ln_b,
    const float* __restrict__ cls_w,     // (ND, NCLS)
    const float* __restrict__ cls_b,     // (NCLS,)
    const float* __restrict__ aux_w,     // (ND, NORG)
    const float* __restrict__ aux_b,     // (NORG,)
    float* __restrict__ out_logits,      // (NB, NCLS)
    float* __restrict__ out_aux,         // (NB, NORG)
    float* __restrict__ probs_out,       // (NTOK, NE)
    float* __restrict__ ent_out)         // (NTOK,)
{
    const int t = threadIdx.x;

    if (blockIdx.x < RBLKS) {
        // ------------------------------ router ------------------------------
        __shared__ __align__(16) float s_w[NE][8][100];  // [expert][slice][96+4]
        __shared__ float s_worg[NORG][NE];
        __shared__ float s_rb[NE];

        for (int i = t; i < ND * NE; i += 256) {
            const int d = i >> 3, e = i & 7;
            s_w[e][d / KSL][d % KSL] = rw[i];
        }
        if (t < NORG * NE) {
            const int o = t >> 3, e = t & 7;
            s_worg[o][e] = rw[(ND + o) * NE + e];
        }
        if (t < NE) s_rb[t] = rb[t];
        __syncthreads();

        const int lane = t & 63;
        const int wid  = t >> 6;
        const int s    = lane & 7;       // k-slice
        const int tg   = lane >> 3;      // token within wave
        const int token = blockIdx.x * 32 + wid * 8 + tg;

        const int b  = token / NT;
        const int tt = token - b * NT;
        const float* xp = tokens + ((size_t)b * NT_ALL + 1 + tt) * ND + s * KSL;

        float acc[NE];
#pragma unroll
        for (int e = 0; e < NE; ++e) acc[e] = 0.f;

#pragma unroll 8
        for (int j = 0; j < KSL / 4; ++j) {
            const float4 x4 = *reinterpret_cast<const float4*>(xp + j * 4);
#pragma unroll
            for (int e = 0; e < NE; ++e) {
                const float4 w4 = *reinterpret_cast<const float4*>(&s_w[e][s][j * 4]);
                acc[e] = fmaf(x4.x, w4.x, acc[e]);
                acc[e] = fmaf(x4.y, w4.y, acc[e]);
                acc[e] = fmaf(x4.z, w4.z, acc[e]);
                acc[e] = fmaf(x4.w, w4.w, acc[e]);
            }
        }

        // Reduce the 8 k-slices (adjacent lanes): 3-stage butterfly.
#pragma unroll
        for (int off = 1; off <= 4; off <<= 1) {
#pragma unroll
            for (int e = 0; e < NE; ++e)
                acc[e] += __shfl_xor(acc[e], off, 64);
        }

        // Bias + organ-prior logits (per lane; priors L1-cached).
        float pr[NORG];
#pragma unroll
        for (int o = 0; o < NORG; ++o) pr[o] = priors[b * NORG + o];
#pragma unroll
        for (int e = 0; e < NE; ++e) {
            float a = acc[e] + s_rb[e];
#pragma unroll
            for (int o = 0; o < NORG; ++o)
                a = fmaf(pr[o], s_worg[o][e], a);
            acc[e] = a;
        }

        // Per-lane softmax + entropy:  ent = ln(S) - (sum p*l)/S, l = logit-max
        float m = acc[0];
#pragma unroll
        for (int e = 1; e < NE; ++e) m = fmaxf(m, acc[e]);
        float S = 0.f, dd = 0.f;
#pragma unroll
        for (int e = 0; e < NE; ++e) {
            const float l = acc[e] - m;
            const float p = __expf(l);
            acc[e] = p;
            S += p;
            dd = fmaf(p, l, dd);
        }
        const float inv = 1.f / S;
        const float ent = __logf(S) - dd * inv;

        // This lane stores expert s: static-index select chain.
        float pv = acc[0] * inv;
#pragma unroll
        for (int e = 1; e < NE; ++e)
            pv = (s == e) ? acc[e] * inv : pv;

        probs_out[(size_t)token * NE + s] = pv;   // contiguous 256B per wave
        if (s == 0) ent_out[token] = ent;
    } else {
        // ------------------------------ CLS head ----------------------------
        const int cb   = blockIdx.x - RBLKS;     // 0..255
        const int b    = cb >> 1;
        const int half = cb & 1;
        const int lane = t & 63;
        const int wv   = t >> 6;                 // 0..3

        __shared__ __align__(16) float s_x[ND];
        __shared__ float s_red[4];
        __shared__ float s_part[4][65];

        const float* xp = tokens + (size_t)b * NT_ALL * ND;  // cls token

        float sum = 0.f;
        for (int i = t; i < ND; i += 256) { float v = xp[i]; s_x[i] = v; sum += v; }
#pragma unroll
        for (int off = 32; off; off >>= 1) sum += __shfl_xor(sum, off, 64);
        if (lane == 0) s_red[wv] = sum;
        __syncthreads();
        float mu = (s_red[0] + s_red[1] + s_red[2] + s_red[3]) * (1.f / ND);
        __syncthreads();

        float sq = 0.f;
        for (int i = t; i < ND; i += 256) { float d = s_x[i] - mu; sq += d * d; }
#pragma unroll
        for (int off = 32; off; off >>= 1) sq += __shfl_xor(sq, off, 64);
        if (lane == 0) s_red[wv] = sq;
        __syncthreads();
        const float var  = (s_red[0] + s_red[1] + s_red[2] + s_red[3]) * (1.f / ND);
        const float rstd = rsqrtf(var + 1e-5f);
        __syncthreads();

        for (int i = t; i < ND; i += 256)
            s_x[i] = (s_x[i] - mu) * rstd * ln_g[i] + ln_b[i];
        __syncthreads();

        // GEMV: column c = half*64+lane; K-split across 4 waves (192 dims ea).
        const int c = half * 64 + lane;
        const float* wp; int st;
        if (c < NCLS)      { wp = cls_w + c;          st = NCLS; }
        else if (c < NCOL) { wp = aux_w + (c - NCLS); st = NORG; }
        else               { wp = aux_w;              st = NORG; }

        const int d0 = wv * 192;
        const float* w = wp + (size_t)d0 * st;
        const int st2 = 2 * st, st3 = 3 * st, st4 = 4 * st;
        float a0 = 0.f, a1 = 0.f, a2 = 0.f, a3 = 0.f;
#pragma unroll 8
        for (int j = 0; j < 192; j += 4) {
            const float4 x4 = *reinterpret_cast<const float4*>(&s_x[d0 + j]);
            a0 = fmaf(x4.x, w[0],   a0);
            a1 = fmaf(x4.y, w[st],  a1);
            a2 = fmaf(x4.z, w[st2], a2);
            a3 = fmaf(x4.w, w[st3], a3);
            w += st4;
        }
        s_part[wv][lane] = (a0 + a1) + (a2 + a3);
        __syncthreads();

        if (t < 64) {
            float r = s_part[0][t] + s_part[1][t] + s_part[2][t] + s_part[3][t];
            const int cc = half * 64 + t;
            if (cc < NCLS)
                out_logits[b * NCLS + cc] = r + cls_b[cc];
            else if (cc < NCOL)
                out_aux[b * NORG + (cc - NCLS)] = r + aux_b[cc - NCLS];
        }
    }
}

extern "C" void kernel_launch(void* const* d_in, const int* in_sizes, int n_in,
                              void* d_out, int out_size, void* d_ws, size_t ws_size,
                              hipStream_t stream) {
    const float* tokens = (const float*)d_in[0];
    const float* priors = (const float*)d_in[1];
    const float* rw     = (const float*)d_in[2];
    const float* rb     = (const float*)d_in[3];
    // d_in[4..7] = w1,b1,w2,b2 : dead code (MoE output unused by reference)
    const float* ln_g   = (const float*)d_in[8];
    const float* ln_b   = (const float*)d_in[9];
    const float* cls_w  = (const float*)d_in[10];
    const float* cls_b  = (const float*)d_in[11];
    const float* aux_w  = (const float*)d_in[12];
    const float* aux_b  = (const float*)d_in[13];

    float* out = (float*)d_out;
    float* out_logits = out;                                   // 12800
    float* out_aux    = out + NB * NCLS;                       // +640
    float* out_probs  = out + NB * NCLS + NB * NORG;           // +200704
    float* out_ent    = out + NB * NCLS + NB * NORG + (size_t)NTOK * NE;

    fused_kernel<<<RBLKS + CBLKS, 256, 0, stream>>>(
        tokens, priors, rw, rb, ln_g, ln_b, cls_w, cls_b, aux_w, aux_b,
        out_logits, out_aux, out_probs, out_ent);
}

// Round 5
// 26.230 us; speedup vs baseline: 3.5427x; 1.6001x over previous
//
#include <hip/hip_runtime.h>
#include <hip/hip_bf16.h>
#include <math.h>

// Problem constants (from reference)
#define NB     128
#define NT_ALL 197
#define NT     196
#define ND     768
#define NORG   5
#define NE     8
#define NCLS   100
#define NCOL   105            // 100 cls + 5 aux columns
#define NTOK   (NB * NT)      // 25088
#define KB     24             // 768 / 32 k-blocks

#define CBLKS  256            // cls blocks (first in grid: short, fill CUs)
#define RBLKS  392            // router blocks: 392 * 4 waves * 16 tokens = 25088

typedef short  bf16x8 __attribute__((ext_vector_type(8)));
typedef float  f32x4  __attribute__((ext_vector_type(4)));

// Output layout (flat, concatenated in return order):
//   logits  : NB*NCLS = 12800   @ 0
//   aux_org : NB*NORG = 640     @ 12800
//   probs   : NTOK*NE = 200704  @ 13440
//   entropy : NTOK    = 25088   @ 214144

// ---------------------------------------------------------------------------
// Router-as-GEMM: D[e][t] = sum_k W[k][e] * X[t][k] via mfma_f32_16x16x32_bf16.
// A = W^T (16 expert rows, 8 real + 8 zero), B = X^T (K x 16 tokens).
// D layout: col(lane&15)=token, row((lane>>4)*4+reg)=expert -> token t's 8
// experts in lanes {t, t+16}; one shfl_xor(16) then per-lane softmax tail.
// ---------------------------------------------------------------------------
__global__ __launch_bounds__(256, 4) void fused_kernel(
    const float* __restrict__ tokens,    // (NB, NT_ALL, ND)
    const float* __restrict__ priors,    // (NB, NORG)
    const float* __restrict__ rw,        // (ND+NORG, NE) row-major
    const float* __restrict__ rbias,     // (NE,)
    const float* __restrict__ ln_g, const float* __restrict__ ln_b,
    const float* __restrict__ cls_w,     // (ND, NCLS)
    const float* __restrict__ cls_b,     // (NCLS,)
    const float* __restrict__ aux_w,     // (ND, NORG)
    const float* __restrict__ aux_b,     // (NORG,)
    float* __restrict__ out_logits,      // (NB, NCLS)
    float* __restrict__ out_aux,         // (NB, NORG)
    float* __restrict__ probs_out,       // (NTOK, NE)
    float* __restrict__ ent_out)         // (NTOK,)
{
    const int t = threadIdx.x;

    if (blockIdx.x >= CBLKS) {
        // ------------------------------ router ------------------------------
        const int rblk = blockIdx.x - CBLKS;      // 0..391

        // A-fragments: [kb][g][e][8 bf16], e in 0..15 (8..15 zero-padded).
        __shared__ __align__(16) __hip_bfloat16 s_a[KB * 4 * 16 * 8]; // 24KB
        __shared__ float s_pl[2][NE];

        // Zero-init (covers the e>=8 padding), vectorized.
        {
            bf16x8 z = {0, 0, 0, 0, 0, 0, 0, 0};
            bf16x8* p = (bf16x8*)s_a;
            for (int i = t; i < KB * 4 * 16; i += 256) p[i] = z;
        }
        __syncthreads();

        // Fill real experts: coalesced rw reads, scattered b16 LDS writes.
        for (int i = t; i < ND * NE; i += 256) {
            const int k = i >> 3, e = i & 7;
            const int kb = k >> 5, g = (k >> 3) & 3, j = k & 7;
            s_a[(((kb * 4 + g) * 16) + e) * 8 + j] = __float2bfloat16(rw[i]);
        }

        // Prior+bias logits for the (at most 2) batch rows this block spans.
        const int tok0 = rblk * 64;
        const int b0 = tok0 / NT;
        const int b1 = (tok0 + 63) / NT;
        if (t < 16) {
            const int e = t & 7, which = t >> 3;
            const int b = which ? b1 : b0;
            float a = rbias[e];
#pragma unroll
            for (int o = 0; o < NORG; ++o)
                a = fmaf(priors[b * NORG + o], rw[(ND + o) * NE + e], a);
            s_pl[which][e] = a;
        }
        __syncthreads();

        const int wid  = t >> 6;
        const int lane = t & 63;
        const int gbase = tok0 + wid * 16;        // this wave's 16 tokens
        const int tt = lane & 15;                 // token col / expert row
        const int g  = lane >> 4;                 // k-octet selector
        const int token = gbase + tt;
        const int b  = token / NT;
        const float* xp = tokens + ((size_t)b * NT_ALL + 1 + (token - b * NT)) * ND
                          + g * 8;

        const bf16x8* s_a8 = (const bf16x8*)s_a;
        f32x4 acc = {0.f, 0.f, 0.f, 0.f};

#pragma unroll 8
        for (int kb = 0; kb < KB; ++kb) {
            const float4 x0 = *reinterpret_cast<const float4*>(xp + kb * 32);
            const float4 x1 = *reinterpret_cast<const float4*>(xp + kb * 32 + 4);
            union { bf16x8 v; __hip_bfloat16 h[8]; } u;
            u.h[0] = __float2bfloat16(x0.x);
            u.h[1] = __float2bfloat16(x0.y);
            u.h[2] = __float2bfloat16(x0.z);
            u.h[3] = __float2bfloat16(x0.w);
            u.h[4] = __float2bfloat16(x1.x);
            u.h[5] = __float2bfloat16(x1.y);
            u.h[6] = __float2bfloat16(x1.z);
            u.h[7] = __float2bfloat16(x1.w);
            const bf16x8 af = s_a8[(kb * 4 + g) * 16 + tt];
            acc = __builtin_amdgcn_mfma_f32_16x16x32_bf16(af, u.v, acc, 0, 0, 0);
        }

        // Gather the other 4 experts from lane^16.
        const float p0 = __shfl_xor(acc[0], 16, 64);
        const float p1 = __shfl_xor(acc[1], 16, 64);
        const float p2 = __shfl_xor(acc[2], 16, 64);
        const float p3 = __shfl_xor(acc[3], 16, 64);

        if (lane < 16) {
            float lg[NE] = {acc[0], acc[1], acc[2], acc[3], p0, p1, p2, p3};
            const int bsel = (token >= (b0 + 1) * NT) ? 1 : 0;
#pragma unroll
            for (int e = 0; e < NE; ++e) lg[e] += s_pl[bsel][e];

            // softmax + entropy: ent = ln(S) - (sum p*l)/S, l = logit - max
            float m = lg[0];
#pragma unroll
            for (int e = 1; e < NE; ++e) m = fmaxf(m, lg[e]);
            float S = 0.f, dd = 0.f;
#pragma unroll
            for (int e = 0; e < NE; ++e) {
                const float l = lg[e] - m;
                const float p = __expf(l);
                lg[e] = p;
                S += p;
                dd = fmaf(p, l, dd);
            }
            const float inv = 1.f / S;
            const float ent = __logf(S) - dd * inv;

            float4 q0 = {lg[0] * inv, lg[1] * inv, lg[2] * inv, lg[3] * inv};
            float4 q1 = {lg[4] * inv, lg[5] * inv, lg[6] * inv, lg[7] * inv};
            *reinterpret_cast<float4*>(probs_out + (size_t)token * NE)     = q0;
            *reinterpret_cast<float4*>(probs_out + (size_t)token * NE + 4) = q1;
            ent_out[token] = ent;
        }
    } else {
        // ------------------------------ CLS head ----------------------------
        const int cb   = blockIdx.x;             // 0..255
        const int b    = cb >> 1;
        const int half = cb & 1;
        const int lane = t & 63;
        const int wv   = t >> 6;                 // 0..3

        __shared__ __align__(16) float s_x[ND];
        __shared__ float s_red[4];
        __shared__ float s_part[4][65];

        const float* xp = tokens + (size_t)b * NT_ALL * ND;  // cls token

        float sum = 0.f;
        for (int i = t; i < ND; i += 256) { float v = xp[i]; s_x[i] = v; sum += v; }
#pragma unroll
        for (int off = 32; off; off >>= 1) sum += __shfl_xor(sum, off, 64);
        if (lane == 0) s_red[wv] = sum;
        __syncthreads();
        const float mu = (s_red[0] + s_red[1] + s_red[2] + s_red[3]) * (1.f / ND);
        __syncthreads();

        float sq = 0.f;
        for (int i = t; i < ND; i += 256) { float d = s_x[i] - mu; sq += d * d; }
#pragma unroll
        for (int off = 32; off; off >>= 1) sq += __shfl_xor(sq, off, 64);
        if (lane == 0) s_red[wv] = sq;
        __syncthreads();
        const float var  = (s_red[0] + s_red[1] + s_red[2] + s_red[3]) * (1.f / ND);
        const float rstd = rsqrtf(var + 1e-5f);
        __syncthreads();

        for (int i = t; i < ND; i += 256)
            s_x[i] = (s_x[i] - mu) * rstd * ln_g[i] + ln_b[i];
        __syncthreads();

        const int c = half * 64 + lane;
        const float* wp; int st;
        if (c < NCLS)      { wp = cls_w + c;          st = NCLS; }
        else if (c < NCOL) { wp = aux_w + (c - NCLS); st = NORG; }
        else               { wp = aux_w;              st = NORG; }

        const int d0 = wv * 192;
        const float* w = wp + (size_t)d0 * st;
        const int st2 = 2 * st, st3 = 3 * st, st4 = 4 * st;
        float a0 = 0.f, a1 = 0.f, a2 = 0.f, a3 = 0.f;
#pragma unroll 8
        for (int j = 0; j < 192; j += 4) {
            const float4 x4 = *reinterpret_cast<const float4*>(&s_x[d0 + j]);
            a0 = fmaf(x4.x, w[0],   a0);
            a1 = fmaf(x4.y, w[st],  a1);
            a2 = fmaf(x4.z, w[st2], a2);
            a3 = fmaf(x4.w, w[st3], a3);
            w += st4;
        }
        s_part[wv][lane] = (a0 + a1) + (a2 + a3);
        __syncthreads();

        if (t < 64) {
            float r = s_part[0][t] + s_part[1][t] + s_part[2][t] + s_part[3][t];
            const int cc = half * 64 + t;
            if (cc < NCLS)
                out_logits[b * NCLS + cc] = r + cls_b[cc];
            else if (cc < NCOL)
                out_aux[b * NORG + (cc - NCLS)] = r + aux_b[cc - NCLS];
        }
    }
}

extern "C" void kernel_launch(void* const* d_in, const int* in_sizes, int n_in,
                              void* d_out, int out_size, void* d_ws, size_t ws_size,
                              hipStream_t stream) {
    const float* tokens = (const float*)d_in[0];
    const float* priors = (const float*)d_in[1];
    const float* rw     = (const float*)d_in[2];
    const float* rbias  = (const float*)d_in[3];
    // d_in[4..7] = w1,b1,w2,b2 : dead code (MoE output unused by reference)
    const float* ln_g   = (const float*)d_in[8];
    const float* ln_b   = (const float*)d_in[9];
    const float* cls_w  = (const float*)d_in[10];
    const float* cls_b  = (const float*)d_in[11];
    const float* aux_w  = (const float*)d_in[12];
    const float* aux_b  = (const float*)d_in[13];

    float* out = (float*)d_out;
    float* out_logits = out;                                   // 12800
    float* out_aux    = out + NB * NCLS;                       // +640
    float* out_probs  = out + NB * NCLS + NB * NORG;           // +200704
    float* out_ent    = out + NB * NCLS + NB * NORG + (size_t)NTOK * NE;

    fused_kernel<<<CBLKS + RBLKS, 256, 0, stream>>>(
        tokens, priors, rw, rbias, ln_g, ln_b, cls_w, cls_b, aux_w, aux_b,
        out_logits, out_aux, out_probs, out_ent);
}

// Round 6
// 25.964 us; speedup vs baseline: 3.5789x; 1.0102x over previous
//
#include <hip/hip_runtime.h>
#include <hip/hip_bf16.h>
#include <math.h>

// Problem constants (from reference)
#define NB     128
#define NT_ALL 197
#define NT     196
#define ND     768
#define NORG   5
#define NE     8
#define NCLS   100
#define NCOL   105            // 100 cls + 5 aux columns
#define NTOK   (NB * NT)      // 25088
#define KB     24             // 768 / 32 k-blocks
#define PF     6              // prefetch depth (k-blocks in flight)

#define CBLKS  256            // cls blocks (first in grid: short, fill CUs)
#define RBLKS  392            // router blocks: 392 * 4 waves * 16 tokens = 25088

typedef short  bf16x8 __attribute__((ext_vector_type(8)));
typedef float  f32x4  __attribute__((ext_vector_type(4)));

// Output layout (flat, concatenated in return order):
//   logits  : NB*NCLS = 12800   @ 0
//   aux_org : NB*NORG = 640     @ 12800
//   probs   : NTOK*NE = 200704  @ 13440
//   entropy : NTOK    = 25088   @ 214144

// ---------------------------------------------------------------------------
// Router-as-GEMM: D[e][t] = sum_k W[k][e] * X[t][k] via mfma_f32_16x16x32_bf16.
// A = W^T (16 expert rows, 8 real + 8 zero), B = X^T (K x 16 tokens).
// R6: 6-deep explicit x-prefetch ring (prologue issued BEFORE staging so HBM
// latency hides under it), split even/odd accumulator chains, single barrier.
// ---------------------------------------------------------------------------
__global__ __launch_bounds__(256, 4) void fused_kernel(
    const float* __restrict__ tokens,    // (NB, NT_ALL, ND)
    const float* __restrict__ priors,    // (NB, NORG)
    const float* __restrict__ rw,        // (ND+NORG, NE) row-major
    const float* __restrict__ rbias,     // (NE,)
    const float* __restrict__ ln_g, const float* __restrict__ ln_b,
    const float* __restrict__ cls_w,     // (ND, NCLS)
    const float* __restrict__ cls_b,     // (NCLS,)
    const float* __restrict__ aux_w,     // (ND, NORG)
    const float* __restrict__ aux_b,     // (NORG,)
    float* __restrict__ out_logits,      // (NB, NCLS)
    float* __restrict__ out_aux,         // (NB, NORG)
    float* __restrict__ probs_out,       // (NTOK, NE)
    float* __restrict__ ent_out)         // (NTOK,)
{
    const int t = threadIdx.x;

    if (blockIdx.x >= CBLKS) {
        // ------------------------------ router ------------------------------
        const int rblk = blockIdx.x - CBLKS;      // 0..391

        // A-fragments: [kb][g][e][8 bf16], e in 0..15 (8..15 zero-padded).
        __shared__ __align__(16) __hip_bfloat16 s_a[KB * 4 * 16 * 8]; // 24KB
        __shared__ float s_pl[2][NE];

        const int wid  = t >> 6;
        const int lane = t & 63;
        const int tok0 = rblk * 64;
        const int gbase = tok0 + wid * 16;        // this wave's 16 tokens
        const int tt = lane & 15;                 // token col / expert row
        const int g  = lane >> 4;                 // k-octet selector
        const int token = gbase + tt;
        const int b  = token / NT;
        const float* xp = tokens + ((size_t)b * NT_ALL + 1 + (token - b * NT)) * ND
                          + g * 8;

        // Prologue x-prefetch: issue BEFORE staging so latency overlaps it.
        float4 xb[PF][2];
#pragma unroll
        for (int i = 0; i < PF; ++i) {
            xb[i][0] = *reinterpret_cast<const float4*>(xp + i * 32);
            xb[i][1] = *reinterpret_cast<const float4*>(xp + i * 32 + 4);
        }

        // Zero-init ONLY the e>=8 padding rows (disjoint from fill below).
        {
            bf16x8 z = {0, 0, 0, 0, 0, 0, 0, 0};
            bf16x8* p = (bf16x8*)s_a;
            for (int i = t; i < KB * 4 * 8; i += 256)
                p[(i >> 3) * 16 + 8 + (i & 7)] = z;
        }
        // Fill real experts (e<8): coalesced rw reads, scattered b16 writes.
        for (int i = t; i < ND * NE; i += 256) {
            const int k = i >> 3, e = i & 7;
            const int kb = k >> 5, gg = (k >> 3) & 3, j = k & 7;
            s_a[(((kb * 4 + gg) * 16) + e) * 8 + j] = __float2bfloat16(rw[i]);
        }
        // Prior+bias logits for the (at most 2) batch rows this block spans.
        const int b0 = tok0 / NT;
        const int b1 = (tok0 + 63) / NT;
        if (t < 16) {
            const int e = t & 7, which = t >> 3;
            const int bb = which ? b1 : b0;
            float a = rbias[e];
#pragma unroll
            for (int o = 0; o < NORG; ++o)
                a = fmaf(priors[bb * NORG + o], rw[(ND + o) * NE + e], a);
            s_pl[which][e] = a;
        }
        __syncthreads();   // single barrier: zero/fill regions are disjoint

        const bf16x8* s_a8 = (const bf16x8*)s_a;
        f32x4 acc0 = {0.f, 0.f, 0.f, 0.f};
        f32x4 acc1 = {0.f, 0.f, 0.f, 0.f};

#pragma unroll
        for (int kb = 0; kb < KB; ++kb) {
            const float4 x0 = xb[kb % PF][0];
            const float4 x1 = xb[kb % PF][1];
            union { bf16x8 v; __hip_bfloat16 h[8]; } u;
            u.h[0] = __float2bfloat16(x0.x);
            u.h[1] = __float2bfloat16(x0.y);
            u.h[2] = __float2bfloat16(x0.z);
            u.h[3] = __float2bfloat16(x0.w);
            u.h[4] = __float2bfloat16(x1.x);
            u.h[5] = __float2bfloat16(x1.y);
            u.h[6] = __float2bfloat16(x1.z);
            u.h[7] = __float2bfloat16(x1.w);
            const bf16x8 af = s_a8[(kb * 4 + g) * 16 + tt];
            if (kb & 1)
                acc1 = __builtin_amdgcn_mfma_f32_16x16x32_bf16(af, u.v, acc1, 0, 0, 0);
            else
                acc0 = __builtin_amdgcn_mfma_f32_16x16x32_bf16(af, u.v, acc0, 0, 0, 0);
            if (kb + PF < KB) {
                xb[kb % PF][0] = *reinterpret_cast<const float4*>(xp + (kb + PF) * 32);
                xb[kb % PF][1] = *reinterpret_cast<const float4*>(xp + (kb + PF) * 32 + 4);
            }
        }
        const f32x4 acc = acc0 + acc1;

        // Gather the other 4 experts from lane^16.
        const float p0 = __shfl_xor(acc[0], 16, 64);
        const float p1 = __shfl_xor(acc[1], 16, 64);
        const float p2 = __shfl_xor(acc[2], 16, 64);
        const float p3 = __shfl_xor(acc[3], 16, 64);

        if (lane < 16) {
            float lg[NE] = {acc[0], acc[1], acc[2], acc[3], p0, p1, p2, p3};
            const int bsel = (token >= (b0 + 1) * NT) ? 1 : 0;
#pragma unroll
            for (int e = 0; e < NE; ++e) lg[e] += s_pl[bsel][e];

            // softmax + entropy: ent = ln(S) - (sum p*l)/S, l = logit - max
            float m = lg[0];
#pragma unroll
            for (int e = 1; e < NE; ++e) m = fmaxf(m, lg[e]);
            float S = 0.f, dd = 0.f;
#pragma unroll
            for (int e = 0; e < NE; ++e) {
                const float l = lg[e] - m;
                const float p = __expf(l);
                lg[e] = p;
                S += p;
                dd = fmaf(p, l, dd);
            }
            const float inv = 1.f / S;
            const float ent = __logf(S) - dd * inv;

            float4 q0 = {lg[0] * inv, lg[1] * inv, lg[2] * inv, lg[3] * inv};
            float4 q1 = {lg[4] * inv, lg[5] * inv, lg[6] * inv, lg[7] * inv};
            *reinterpret_cast<float4*>(probs_out + (size_t)token * NE)     = q0;
            *reinterpret_cast<float4*>(probs_out + (size_t)token * NE + 4) = q1;
            ent_out[token] = ent;
        }
    } else {
        // ------------------------------ CLS head ----------------------------
        const int cb   = blockIdx.x;             // 0..255
        const int b    = cb >> 1;
        const int half = cb & 1;
        const int lane = t & 63;
        const int wv   = t >> 6;                 // 0..3

        __shared__ __align__(16) float s_x[ND];
        __shared__ float s_red[4];
        __shared__ float s_part[4][65];

        const float* xp = tokens + (size_t)b * NT_ALL * ND;  // cls token

        float sum = 0.f;
        for (int i = t; i < ND; i += 256) { float v = xp[i]; s_x[i] = v; sum += v; }
#pragma unroll
        for (int off = 32; off; off >>= 1) sum += __shfl_xor(sum, off, 64);
        if (lane == 0) s_red[wv] = sum;
        __syncthreads();
        const float mu = (s_red[0] + s_red[1] + s_red[2] + s_red[3]) * (1.f / ND);
        __syncthreads();

        float sq = 0.f;
        for (int i = t; i < ND; i += 256) { float d = s_x[i] - mu; sq += d * d; }
#pragma unroll
        for (int off = 32; off; off >>= 1) sq += __shfl_xor(sq, off, 64);
        if (lane == 0) s_red[wv] = sq;
        __syncthreads();
        const float var  = (s_red[0] + s_red[1] + s_red[2] + s_red[3]) * (1.f / ND);
        const float rstd = rsqrtf(var + 1e-5f);
        __syncthreads();

        for (int i = t; i < ND; i += 256)
            s_x[i] = (s_x[i] - mu) * rstd * ln_g[i] + ln_b[i];
        __syncthreads();

        const int c = half * 64 + lane;
        const float* wp; int st;
        if (c < NCLS)      { wp = cls_w + c;          st = NCLS; }
        else if (c < NCOL) { wp = aux_w + (c - NCLS); st = NORG; }
        else               { wp = aux_w;              st = NORG; }

        const int d0 = wv * 192;
        const float* w = wp + (size_t)d0 * st;
        const int st2 = 2 * st, st3 = 3 * st, st4 = 4 * st;
        float a0 = 0.f, a1 = 0.f, a2 = 0.f, a3 = 0.f;
#pragma unroll 8
        for (int j = 0; j < 192; j += 4) {
            const float4 x4 = *reinterpret_cast<const float4*>(&s_x[d0 + j]);
            a0 = fmaf(x4.x, w[0],   a0);
            a1 = fmaf(x4.y, w[st],  a1);
            a2 = fmaf(x4.z, w[st2], a2);
            a3 = fmaf(x4.w, w[st3], a3);
            w += st4;
        }
        s_part[wv][lane] = (a0 + a1) + (a2 + a3);
        __syncthreads();

        if (t < 64) {
            float r = s_part[0][t] + s_part[1][t] + s_part[2][t] + s_part[3][t];
            const int cc = half * 64 + t;
            if (cc < NCLS)
                out_logits[b * NCLS + cc] = r + cls_b[cc];
            else if (cc < NCOL)
                out_aux[b * NORG + (cc - NCLS)] = r + aux_b[cc - NCLS];
        }
    }
}

extern "C" void kernel_launch(void* const* d_in, const int* in_sizes, int n_in,
                              void* d_out, int out_size, void* d_ws, size_t ws_size,
                              hipStream_t stream) {
    const float* tokens = (const float*)d_in[0];
    const float* priors = (const float*)d_in[1];
    const float* rw     = (const float*)d_in[2];
    const float* rbias  = (const float*)d_in[3];
    // d_in[4..7] = w1,b1,w2,b2 : dead code (MoE output unused by reference)
    const float* ln_g   = (const float*)d_in[8];
    const float* ln_b   = (const float*)d_in[9];
    const float* cls_w  = (const float*)d_in[10];
    const float* cls_b  = (const float*)d_in[11];
    const float* aux_w  = (const float*)d_in[12];
    const float* aux_b  = (const float*)d_in[13];

    float* out = (float*)d_out;
    float* out_logits = out;                                   // 12800
    float* out_aux    = out + NB * NCLS;                       // +640
    float* out_probs  = out + NB * NCLS + NB * NORG;           // +200704
    float* out_ent    = out + NB * NCLS + NB * NORG + (size_t)NTOK * NE;

    fused_kernel<<<CBLKS + RBLKS, 256, 0, stream>>>(
        tokens, priors, rw, rbias, ln_g, ln_b, cls_w, cls_b, aux_w, aux_b,
        out_logits, out_aux, out_probs, out_ent);
}